// Round 4
// baseline (338.464 us; speedup 1.0000x reference)
//
#include <hip/hip_runtime.h>
#include <hip/hip_bf16.h>

#define L 1024
#define D 128
#define NB 32
#define BQ 16

typedef __attribute__((ext_vector_type(8))) short short8;
typedef __attribute__((ext_vector_type(4))) short short4v;
typedef __attribute__((ext_vector_type(4))) float f32x4;

__device__ __forceinline__ unsigned short f2bf(float f) {
    union { float f; unsigned int u; } x; x.f = f;
    unsigned int r = x.u + 0x7FFF + ((x.u >> 16) & 1);
    return (unsigned short)(r >> 16);
}
__device__ __forceinline__ float bf2f(unsigned short u) {
    union { unsigned int u; float f; } x; x.u = ((unsigned int)u) << 16;
    return x.f;
}
__device__ __forceinline__ float fast_exp2(float x) {
#if __has_builtin(__builtin_amdgcn_exp2f)
    return __builtin_amdgcn_exp2f(x);
#else
    return exp2f(x);
#endif
}

// ---------------------------------------------------------------------------
// Prep kernel (one launch):
//   blocks [0, 2048):    K fp32 [B][L][D] -> Kb bf16 [B][L][D]  (coalesced)
//   blocks [2048, 6144): V fp32 [B][L][D] -> Vt bf16 [B][D][L]  (32x32 LDS transpose)
// ---------------------------------------------------------------------------
__global__ void prep_kernel(const float* __restrict__ K, const float* __restrict__ V,
                            unsigned short* __restrict__ Kb, unsigned short* __restrict__ Vt) {
    __shared__ unsigned short t[32][40];
    int id = blockIdx.x;
    int tid = threadIdx.x;
    if (id < 2048) {
        size_t base = (size_t)id * 2048 + (size_t)tid * 8;
        float4 a = *(const float4*)(K + base);
        float4 c = *(const float4*)(K + base + 4);
        short8 o;
        o[0] = (short)f2bf(a.x); o[1] = (short)f2bf(a.y);
        o[2] = (short)f2bf(a.z); o[3] = (short)f2bf(a.w);
        o[4] = (short)f2bf(c.x); o[5] = (short)f2bf(c.y);
        o[6] = (short)f2bf(c.z); o[7] = (short)f2bf(c.w);
        *(short8*)(Kb + base) = o;
        return;
    }
    id -= 2048;
    int b = id >> 7;
    int rest = id & 127;
    int kt = rest >> 2, dt = rest & 3;
    int k0 = kt * 32, d0 = dt * 32;

    int kl = tid >> 3, dl4 = (tid & 7) * 4;
    const float* src = V + (((size_t)b * L + (k0 + kl)) * D) + d0 + dl4;
    float4 v = *(const float4*)src;
    t[dl4 + 0][kl] = f2bf(v.x);
    t[dl4 + 1][kl] = f2bf(v.y);
    t[dl4 + 2][kl] = f2bf(v.z);
    t[dl4 + 3][kl] = f2bf(v.w);
    __syncthreads();

    int dl = tid >> 3, kl4 = (tid & 7) * 4;
    unsigned short* dst = Vt + (((size_t)b * D + (d0 + dl)) * L) + k0 + kl4;
    short4v o;
    o[0] = (short)t[dl][kl4 + 0];
    o[1] = (short)t[dl][kl4 + 1];
    o[2] = (short)t[dl][kl4 + 2];
    o[3] = (short)t[dl][kl4 + 3];
    *(short4v*)dst = o;
}

// ---------------------------------------------------------------------------
// Fused attention: one WG per (batch, 16 q rows), 256 threads / 4 waves.
// kg (83% of HBM traffic) is held fully in 64 VGPRs/thread, loads issued at
// kernel entry and kept in flight through Phase B's MFMA work. A per-thread
// checksum written to LDS right before the Phase-B barrier pins the loads
// early (prevents the compiler sinking them to Phase D — the R2/R3 failure).
// __launch_bounds__(256,2): 256-VGPR budget, no spill.
// ---------------------------------------------------------------------------
__global__ __launch_bounds__(256, 2)
void attn_kernel(const float* __restrict__ Q, const unsigned short* __restrict__ Kb,
                 const float* __restrict__ scale_p, const float* __restrict__ kg,
                 const unsigned short* __restrict__ Vt, float* __restrict__ out) {
    __shared__ unsigned short S16[BQ * 1032];   // 16 x (1024+8) bf16: P -> e
    __shared__ float zpart[4][BQ];              // per-wave partial z1
    __shared__ float row_scale[BQ];             // 1/z2
    __shared__ float dummy[16];                 // checksum sink (never read)

    const int tid = threadIdx.x;
    const int b  = blockIdx.x >> 6;
    const int q0 = (blockIdx.x & 63) * BQ;
    const float nsc = -scale_p[0] * 1.44269504f;   // fold log2e: MFMA out is log2-domain

    const int wave = tid >> 6, lane = tid & 63;
    const int lr = lane & 15;
    const int lg = lane >> 4;
    const int row = tid >> 4, l = tid & 15;     // softmax mapping: 16 thr/row

    // ---- kg prefetch: FULL row slice, 16 x float4 = 64 VGPRs ----------------
    const float* kgrow = kg + (((size_t)b * L) + q0 + row) * L + l * 4;
    float4 kgv[16];
#pragma unroll
    for (int j = 0; j < 16; j++) kgv[j] = *(const float4*)(kgrow + 64 * j);

    // ---- A-fragments straight from global Q (all waves need the same) -------
    short8 aq[4];
#pragma unroll
    for (int kb = 0; kb < 4; kb++) {
        const float* qp = Q + (((size_t)b * L) + q0 + lr) * D + kb * 32 + lg * 8;
        float4 v0 = *(const float4*)qp;
        float4 v1 = *(const float4*)(qp + 4);
        short8 o;
        o[0] = (short)f2bf(v0.x * nsc); o[1] = (short)f2bf(v0.y * nsc);
        o[2] = (short)f2bf(v0.z * nsc); o[3] = (short)f2bf(v0.w * nsc);
        o[4] = (short)f2bf(v1.x * nsc); o[5] = (short)f2bf(v1.y * nsc);
        o[6] = (short)f2bf(v1.z * nsc); o[7] = (short)f2bf(v1.w * nsc);
        aq[kb] = o;
    }

    // ---- Phase B: P = exp2(log2e * S) -> LDS, z1 partials in regs -----------
    f32x4 zp = {0.f, 0.f, 0.f, 0.f};
#pragma unroll 4
    for (int i = 0; i < 16; i++) {
        int ct = wave + i * 4;
        const unsigned short* kp = Kb + (((size_t)b * L) + ct * 16 + lr) * D + lg * 8;
        f32x4 acc = {0.f, 0.f, 0.f, 0.f};
#pragma unroll
        for (int kb = 0; kb < 4; kb++) {
            short8 bf = *(const short8*)(kp + kb * 32);
            acc = __builtin_amdgcn_mfma_f32_16x16x32_bf16(aq[kb], bf, acc, 0, 0, 0);
        }
#pragma unroll
        for (int r = 0; r < 4; r++) {
            float p = fast_exp2(acc[r]);        // = e^S (log2e folded into Q)
            S16[(lg * 4 + r) * 1032 + ct * 16 + lr] = f2bf(p);
            zp[r] += p;
        }
    }
    // reduce z1 partials over lr (low 4 lane bits)
#pragma unroll
    for (int m = 1; m < 16; m <<= 1) {
#pragma unroll
        for (int r = 0; r < 4; r++) zp[r] += __shfl_xor(zp[r], m, 64);
    }
    if (lr == 0) {
#pragma unroll
        for (int r = 0; r < 4; r++) zpart[wave][lg * 4 + r] = zp[r];
    }
    // ---- checksum: pins kg loads BEFORE the barrier (anti-sinking) ----------
    {
        float cs = 0.f;
#pragma unroll
        for (int j = 0; j < 16; j++) cs += kgv[j].x;
        dummy[tid & 15] = cs;   // racy by design; never read
    }
    __syncthreads();   // vmcnt(0): kg fully drained, was in flight all Phase B

    // ---- Phase D: e = exp2(-(P * c1) * kg), single pass, z2 in regs ---------
    const float iz1 = 1.0f / (zpart[0][row] + zpart[1][row] +
                              zpart[2][row] + zpart[3][row]);
    const float c1 = iz1 * 1.44269504f;         // fold log2e
    unsigned short* srow = &S16[row * 1032];
    float z2 = 0.f;
#pragma unroll
    for (int j = 0; j < 16; j++) {
        unsigned short* p = &srow[l * 4 + 64 * j];
        short4v v = *(const short4v*)p;
        float4 g = kgv[j];
        float e0 = fast_exp2(-(bf2f((unsigned short)v[0]) * c1) * g.x);
        float e1 = fast_exp2(-(bf2f((unsigned short)v[1]) * c1) * g.y);
        float e2 = fast_exp2(-(bf2f((unsigned short)v[2]) * c1) * g.z);
        float e3 = fast_exp2(-(bf2f((unsigned short)v[3]) * c1) * g.w);
        z2 += (e0 + e1) + (e2 + e3);
        short4v o; o[0] = (short)f2bf(e0); o[1] = (short)f2bf(e1);
        o[2] = (short)f2bf(e2); o[3] = (short)f2bf(e3);
        *(short4v*)p = o;
    }
#pragma unroll
    for (int m = 1; m < 16; m <<= 1) z2 += __shfl_xor(z2, m, 64);
    if (l == 0) row_scale[row] = 1.0f / z2;
    __syncthreads();

    // ---- Phase E: out = (e @ V) * (1/z2) ------------------------------------
    const int dt0 = wave * 2;
    f32x4 acc0 = {0.f, 0.f, 0.f, 0.f}, acc1 = {0.f, 0.f, 0.f, 0.f};
    const unsigned short* vt0 = Vt + (((size_t)b * D) + dt0 * 16 + lr) * L + lg * 8;
    const unsigned short* vt1 = vt0 + (size_t)16 * L;
    const unsigned short* brow = &S16[lr * 1032 + lg * 8];
#pragma unroll 8
    for (int kb = 0; kb < 32; kb++) {
        short8 a  = *(const short8*)(brow + kb * 32);
        short8 b0 = *(const short8*)(vt0 + kb * 32);
        short8 b1 = *(const short8*)(vt1 + kb * 32);
        acc0 = __builtin_amdgcn_mfma_f32_16x16x32_bf16(a, b0, acc0, 0, 0, 0);
        acc1 = __builtin_amdgcn_mfma_f32_16x16x32_bf16(a, b1, acc1, 0, 0, 0);
    }
    float* orow = out + (((size_t)b * L) + q0) * D;
#pragma unroll
    for (int r = 0; r < 4; r++) {
        int rq = lg * 4 + r;
        float rs = row_scale[rq];
        orow[(size_t)rq * D + dt0 * 16 + lr]       = acc0[r] * rs;
        orow[(size_t)rq * D + (dt0 + 1) * 16 + lr] = acc1[r] * rs;
    }
}

extern "C" void kernel_launch(void* const* d_in, const int* in_sizes, int n_in,
                              void* d_out, int out_size, void* d_ws, size_t ws_size,
                              hipStream_t stream) {
    const float* Q     = (const float*)d_in[0];
    const float* K     = (const float*)d_in[1];
    const float* V     = (const float*)d_in[2];
    const float* scale = (const float*)d_in[3];
    const float* kg    = (const float*)d_in[4];
    float* out = (float*)d_out;
    unsigned short* Vt = (unsigned short*)d_ws;                        // 8 MB
    unsigned short* Kb = (unsigned short*)d_ws + (size_t)NB * D * L;   // 8 MB

    prep_kernel<<<6144, 256, 0, stream>>>(K, V, Kb, Vt);
    attn_kernel<<<NB * (L / BQ), 256, 0, stream>>>(Q, Kb, scale, kg, Vt, out);
}

// Round 5
// 329.149 us; speedup vs baseline: 1.0283x; 1.0283x over previous
//
#include <hip/hip_runtime.h>
#include <hip/hip_bf16.h>

#define L 1024
#define D 128
#define NB 32
#define BQ 16
#define SS 1032          // S16 row stride in u16: 2064B = 129*16 (b128-aligned, +8 pad)
#define KGS 130          // kg LDS row stride in floats: 520B (8B-aligned, 4-way banks)

typedef __attribute__((ext_vector_type(8))) short short8;
typedef __attribute__((ext_vector_type(4))) short short4v;
typedef __attribute__((ext_vector_type(4))) float f32x4;
typedef __attribute__((ext_vector_type(2))) float f32x2;

__device__ __forceinline__ unsigned short f2bf(float f) {
    union { float f; unsigned int u; } x; x.f = f;
    unsigned int r = x.u + 0x7FFF + ((x.u >> 16) & 1);
    return (unsigned short)(r >> 16);
}
__device__ __forceinline__ float bf2f(unsigned short u) {
    union { unsigned int u; float f; } x; x.u = ((unsigned int)u) << 16;
    return x.f;
}
__device__ __forceinline__ float fast_exp2(float x) {
#if __has_builtin(__builtin_amdgcn_exp2f)
    return __builtin_amdgcn_exp2f(x);
#else
    return exp2f(x);
#endif
}
// Async global->LDS DMA, width 4B/lane. Side-effecting: compiler cannot sink it
// (the R2/R3/R4 register-prefetch failure mode).
__device__ __forceinline__ void dma4(const float* g, float* l) {
    __builtin_amdgcn_global_load_lds(
        (const __attribute__((address_space(1))) void*)(const void*)g,
        (__attribute__((address_space(3))) void*)(void*)l, 4, 0, 0);
}

// ---------------------------------------------------------------------------
// Prep kernel (unchanged): K -> bf16 Kb; V -> bf16 transposed Vt.
// ---------------------------------------------------------------------------
__global__ void prep_kernel(const float* __restrict__ K, const float* __restrict__ V,
                            unsigned short* __restrict__ Kb, unsigned short* __restrict__ Vt) {
    __shared__ unsigned short t[32][40];
    int id = blockIdx.x;
    int tid = threadIdx.x;
    if (id < 2048) {
        size_t base = (size_t)id * 2048 + (size_t)tid * 8;
        float4 a = *(const float4*)(K + base);
        float4 c = *(const float4*)(K + base + 4);
        short8 o;
        o[0] = (short)f2bf(a.x); o[1] = (short)f2bf(a.y);
        o[2] = (short)f2bf(a.z); o[3] = (short)f2bf(a.w);
        o[4] = (short)f2bf(c.x); o[5] = (short)f2bf(c.y);
        o[6] = (short)f2bf(c.z); o[7] = (short)f2bf(c.w);
        *(short8*)(Kb + base) = o;
        return;
    }
    id -= 2048;
    int b = id >> 7;
    int rest = id & 127;
    int kt = rest >> 2, dt = rest & 3;
    int k0 = kt * 32, d0 = dt * 32;

    int kl = tid >> 3, dl4 = (tid & 7) * 4;
    const float* src = V + (((size_t)b * L + (k0 + kl)) * D) + d0 + dl4;
    float4 v = *(const float4*)src;
    t[dl4 + 0][kl] = f2bf(v.x);
    t[dl4 + 1][kl] = f2bf(v.y);
    t[dl4 + 2][kl] = f2bf(v.z);
    t[dl4 + 3][kl] = f2bf(v.w);
    __syncthreads();

    int dl = tid >> 3, kl4 = (tid & 7) * 4;
    unsigned short* dst = Vt + (((size_t)b * D + (d0 + dl)) * L) + k0 + kl4;
    short4v o;
    o[0] = (short)t[dl][kl4 + 0];
    o[1] = (short)t[dl][kl4 + 1];
    o[2] = (short)t[dl][kl4 + 2];
    o[3] = (short)t[dl][kl4 + 3];
    *(short4v*)dst = o;
}

// ---------------------------------------------------------------------------
// Fused attention, async-DMA kg pipeline:
//   entry : DMA chunks 0,1 of kg (16KB/WG) -> in flight during Phase B
//   B     : P = exp2(Q'@Kb^T) -> S16, z1 partials (barrier drains DMA 0,1)
//   D     : 8 chunks: wait vmcnt, e = exp2(-(P*c1)*kg) from LDS, issue c+2
//   E     : out = (e @ Vt) / z2
// LDS ~50KB -> 3 WGs/CU. Per-wave DMA: each wave stages only its own 4 rows,
// so vmcnt (per-wave) is the only sync needed inside Phase D.
// ---------------------------------------------------------------------------
__global__ __launch_bounds__(256, 3)
void attn_kernel(const float* __restrict__ Q, const unsigned short* __restrict__ Kb,
                 const float* __restrict__ scale_p, const float* __restrict__ kg,
                 const unsigned short* __restrict__ Vt, float* __restrict__ out) {
    __shared__ unsigned short S16[BQ * SS];     // 33,024 B : P -> e (bf16)
    __shared__ float kgbuf[2][BQ * KGS];        // 16,640 B : kg double buffer
    __shared__ float zpart[4][BQ];
    __shared__ float row_scale[BQ];

    const int tid = threadIdx.x;
    const int b  = blockIdx.x >> 6;
    const int q0 = (blockIdx.x & 63) * BQ;
    const float nsc = -scale_p[0] * 1.44269504f;   // fold log2e into Q

    const int wave = tid >> 6, lane = tid & 63;
    const int lr = lane & 15, lg = lane >> 4;
    const int row = tid >> 4, l = tid & 15;

    const float* kgbase = kg + ((size_t)(b * L + q0)) * L;

    // chunk c (128 cols): wave w stages rows 4w..4w+3, 2 half-rows each (64 floats)
#define ISSUE_CHUNK(c) do {                                                     \
        _Pragma("unroll")                                                       \
        for (int rr = 0; rr < 4; rr++) {                                        \
            const float* s_ = kgbase + (size_t)(4 * wave + rr) * L + (c) * 128 + lane; \
            float* d_ = &kgbuf[(c) & 1][(4 * wave + rr) * KGS];                 \
            dma4(s_, d_);                                                       \
            dma4(s_ + 64, d_ + 64);                                             \
        }                                                                       \
    } while (0)

    ISSUE_CHUNK(0);
    ISSUE_CHUNK(1);

    // ---- A-fragments straight from global Q ---------------------------------
    short8 aq[4];
#pragma unroll
    for (int kb = 0; kb < 4; kb++) {
        const float* qp = Q + (((size_t)b * L) + q0 + lr) * D + kb * 32 + lg * 8;
        float4 v0 = *(const float4*)qp;
        float4 v1 = *(const float4*)(qp + 4);
        short8 o;
        o[0] = (short)f2bf(v0.x * nsc); o[1] = (short)f2bf(v0.y * nsc);
        o[2] = (short)f2bf(v0.z * nsc); o[3] = (short)f2bf(v0.w * nsc);
        o[4] = (short)f2bf(v1.x * nsc); o[5] = (short)f2bf(v1.y * nsc);
        o[6] = (short)f2bf(v1.z * nsc); o[7] = (short)f2bf(v1.w * nsc);
        aq[kb] = o;
    }

    // ---- Phase B: P = exp2(S) -> S16, z1 partials ---------------------------
    f32x4 zp = {0.f, 0.f, 0.f, 0.f};
#pragma unroll 4
    for (int i = 0; i < 16; i++) {
        int ct = wave + i * 4;
        const unsigned short* kp = Kb + (((size_t)b * L) + ct * 16 + lr) * D + lg * 8;
        f32x4 acc = {0.f, 0.f, 0.f, 0.f};
#pragma unroll
        for (int kb = 0; kb < 4; kb++) {
            short8 bf = *(const short8*)(kp + kb * 32);
            acc = __builtin_amdgcn_mfma_f32_16x16x32_bf16(aq[kb], bf, acc, 0, 0, 0);
        }
#pragma unroll
        for (int r = 0; r < 4; r++) {
            float p = fast_exp2(acc[r]);
            S16[(lg * 4 + r) * SS + ct * 16 + lr] = f2bf(p);
            zp[r] += p;
        }
    }
#pragma unroll
    for (int m = 1; m < 16; m <<= 1) {
#pragma unroll
        for (int r = 0; r < 4; r++) zp[r] += __shfl_xor(zp[r], m, 64);
    }
    if (lr == 0) {
#pragma unroll
        for (int r = 0; r < 4; r++) zpart[wave][lg * 4 + r] = zp[r];
    }
    __syncthreads();   // drains vmcnt(0): kg chunks 0,1 landed; overlapped Phase B

    // ---- Phase D: 8-chunk software pipeline ---------------------------------
    const float iz1 = 1.0f / (zpart[0][row] + zpart[1][row] +
                              zpart[2][row] + zpart[3][row]);
    const float c1 = iz1 * 1.44269504f;
    unsigned short* srow = &S16[row * SS];
    float z2 = 0.f;

    auto proc = [&](int cc) {
        const float* gk = &kgbuf[cc & 1][row * KGS + l * 8];
        unsigned short* p = &srow[cc * 128 + l * 8];
        short4v v0 = *(const short4v*)p;
        short4v v1 = *(const short4v*)(p + 4);
        f32x2 g0 = *(const f32x2*)gk;
        f32x2 g1 = *(const f32x2*)(gk + 2);
        f32x2 g2 = *(const f32x2*)(gk + 4);
        f32x2 g3 = *(const f32x2*)(gk + 6);
        float e0 = fast_exp2(-(bf2f((unsigned short)v0[0]) * c1) * g0[0]);
        float e1 = fast_exp2(-(bf2f((unsigned short)v0[1]) * c1) * g0[1]);
        float e2 = fast_exp2(-(bf2f((unsigned short)v0[2]) * c1) * g1[0]);
        float e3 = fast_exp2(-(bf2f((unsigned short)v0[3]) * c1) * g1[1]);
        float e4 = fast_exp2(-(bf2f((unsigned short)v1[0]) * c1) * g2[0]);
        float e5 = fast_exp2(-(bf2f((unsigned short)v1[1]) * c1) * g2[1]);
        float e6 = fast_exp2(-(bf2f((unsigned short)v1[2]) * c1) * g3[0]);
        float e7 = fast_exp2(-(bf2f((unsigned short)v1[3]) * c1) * g3[1]);
        z2 += ((e0 + e1) + (e2 + e3)) + ((e4 + e5) + (e6 + e7));
        short4v o0, o1;
        o0[0] = (short)f2bf(e0); o0[1] = (short)f2bf(e1);
        o0[2] = (short)f2bf(e2); o0[3] = (short)f2bf(e3);
        o1[0] = (short)f2bf(e4); o1[1] = (short)f2bf(e5);
        o1[2] = (short)f2bf(e6); o1[3] = (short)f2bf(e7);
        *(short4v*)p = o0;
        *(short4v*)(p + 4) = o1;
    };

    // vmcnt imms: 0xF78 = vmcnt(8) (next chunk's 8 DMAs may remain), 0xF70 = vmcnt(0)
    proc(0);  ISSUE_CHUNK(2);
    proc(1);  ISSUE_CHUNK(3);
    __builtin_amdgcn_s_waitcnt(0xF78); proc(2); ISSUE_CHUNK(4);
    __builtin_amdgcn_s_waitcnt(0xF78); proc(3); ISSUE_CHUNK(5);
    __builtin_amdgcn_s_waitcnt(0xF78); proc(4); ISSUE_CHUNK(6);
    __builtin_amdgcn_s_waitcnt(0xF78); proc(5); ISSUE_CHUNK(7);
    __builtin_amdgcn_s_waitcnt(0xF78); proc(6);
    __builtin_amdgcn_s_waitcnt(0xF70); proc(7);

#pragma unroll
    for (int m = 1; m < 16; m <<= 1) z2 += __shfl_xor(z2, m, 64);
    if (l == 0) row_scale[row] = 1.0f / z2;
    __syncthreads();

    // ---- Phase E: out = (e @ V) * (1/z2) ------------------------------------
    const int dt0 = wave * 2;
    f32x4 acc0 = {0.f, 0.f, 0.f, 0.f}, acc1 = {0.f, 0.f, 0.f, 0.f};
    const unsigned short* vt0 = Vt + (((size_t)b * D) + dt0 * 16 + lr) * L + lg * 8;
    const unsigned short* vt1 = vt0 + (size_t)16 * L;
    const unsigned short* brow = &S16[lr * SS + lg * 8];
#pragma unroll 8
    for (int kb = 0; kb < 32; kb++) {
        short8 a  = *(const short8*)(brow + kb * 32);
        short8 b0 = *(const short8*)(vt0 + kb * 32);
        short8 b1 = *(const short8*)(vt1 + kb * 32);
        acc0 = __builtin_amdgcn_mfma_f32_16x16x32_bf16(a, b0, acc0, 0, 0, 0);
        acc1 = __builtin_amdgcn_mfma_f32_16x16x32_bf16(a, b1, acc1, 0, 0, 0);
    }
    float* orow = out + (((size_t)b * L) + q0) * D;
#pragma unroll
    for (int r = 0; r < 4; r++) {
        int rq = lg * 4 + r;
        float rs = row_scale[rq];
        orow[(size_t)rq * D + dt0 * 16 + lr]       = acc0[r] * rs;
        orow[(size_t)rq * D + (dt0 + 1) * 16 + lr] = acc1[r] * rs;
    }
#undef ISSUE_CHUNK
}

extern "C" void kernel_launch(void* const* d_in, const int* in_sizes, int n_in,
                              void* d_out, int out_size, void* d_ws, size_t ws_size,
                              hipStream_t stream) {
    const float* Q     = (const float*)d_in[0];
    const float* K     = (const float*)d_in[1];
    const float* V     = (const float*)d_in[2];
    const float* scale = (const float*)d_in[3];
    const float* kg    = (const float*)d_in[4];
    float* out = (float*)d_out;
    unsigned short* Vt = (unsigned short*)d_ws;                        // 8 MB
    unsigned short* Kb = (unsigned short*)d_ws + (size_t)NB * D * L;   // 8 MB

    prep_kernel<<<6144, 256, 0, stream>>>(K, V, Kb, Vt);
    attn_kernel<<<NB * (L / BQ), 256, 0, stream>>>(Q, Kb, scale, kg, Vt, out);
}